// Round 7
// baseline (284.779 us; speedup 1.0000x reference)
//
#include <hip/hip_runtime.h>
#include <hip/hip_bf16.h>

#define DM 256
#define NH 8
#define HD 32
#define NLV 3
#define NPT 4
#define NLP 12
#define BB 16
#define LQ 300
#define NT 8400
#define MROWS (BB * NT)      // 134400
#define QROWS (BB * LQ)      // 4800
#define KP 40                // padded LDS K-stride for BK=32 kernels
#define KP2 72               // padded LDS K-stride for valproj A tile (BK=64)

typedef __bf16 bf16x8 __attribute__((ext_vector_type(8)));
typedef __bf16 bf16x4 __attribute__((ext_vector_type(4)));
typedef float  f32x16 __attribute__((ext_vector_type(16)));

// ---------------------------------------------------------------------------
// Kernel 0: pre-tile weights to bf16.
// blocks 0..255   -> Wf  fragment-major from W_val:
//                    Wf[(k>>3)*2048 + n*8 + (k&7)] = W_val[k][n]
// blocks 256..543 -> Wt2 [ktile(8)][n(288)][k(32)]  from [W_off | W_attn]
// blocks 544..799 -> Wt3 [ktile(8)][n(256)][k(32)]  from W_out
// ---------------------------------------------------------------------------
__global__ void k_wt(const float* __restrict__ W_val,
                     const float* __restrict__ W_off,
                     const float* __restrict__ W_attn,
                     const float* __restrict__ W_out,
                     __hip_bfloat16* __restrict__ Wf,
                     __hip_bfloat16* __restrict__ Wt2,
                     __hip_bfloat16* __restrict__ Wt3)
{
    const int n = blockIdx.x;
    const int k = threadIdx.x;
    if (n < 256) {
        Wf[(size_t)(k >> 3) * 2048 + n * 8 + (k & 7)] =
            __float2bfloat16(W_val[(size_t)k * 256 + n]);
    } else if (n < 544) {
        const int n2 = n - 256;   // 0..287
        float v = (n2 < 192) ? W_off[(size_t)k * 192 + n2]
                             : W_attn[(size_t)k * 96 + (n2 - 192)];
        Wt2[(size_t)(k >> 5) * 9216 + n2 * 32 + (k & 31)] = __float2bfloat16(v);
    } else {
        const int n3 = n - 544;   // 0..255
        Wt3[(size_t)(k >> 5) * 8192 + n3 * 32 + (k & 31)] =
            __float2bfloat16(W_out[(size_t)k * 256 + n3]);
    }
}

// ---------------------------------------------------------------------------
// Kernel 1: value = input_flatten @ W_val + b_val (bf16 MFMA), permuted store.
// Round-7: SWAPPED MFMA OPERANDS -> output is C^T: lane (col) = m row,
// regs (rl) = n.  Each lane owns one V row: 1 division + 8 x bf16x4 stores
// (was 32 divisions + 32 scalar 2-B stores).  K-loop = round-6 (W direct
// from L2 fragment-major, A via double-buffered LDS).
// ---------------------------------------------------------------------------
__global__ __launch_bounds__(256) void k_valproj(
    const float* __restrict__ A,             // (134400, 256) fp32
    const __hip_bfloat16* __restrict__ Wf,   // fragment-major bf16 W
    const float* __restrict__ bias,          // (256,)
    __hip_bfloat16* __restrict__ V)          // (16, 8, 8400, 32)
{
    __shared__ __hip_bfloat16 As[2][32 * KP2];   // 2 x 4.5 KB

    const int t    = threadIdx.x;
    const int m0   = blockIdx.x * 32;
    const int wave = t >> 6;
    const int lane = t & 63;
    const int lm   = lane & 31;
    const int kh   = lane >> 5;      // k-half within 16-step
    const int lk   = kh * 8;

    f32x16 acc[2];
#pragma unroll
    for (int j = 0; j < 2; j++)
#pragma unroll
        for (int e = 0; e < 16; e++) acc[j][e] = 0.f;

    const int ar = t >> 3;          // A row 0..31
    const int ak = (t & 7) * 8;     // A k-chunk 0..56

    const __hip_bfloat16* wf0 = Wf + (size_t)(wave * 64 + lm) * 8 + kh * 2048;

    // prologue: stage A k-tile 0 into buf 0
    {
        const float* ap = A + (size_t)(m0 + ar) * 256 + ak;
        float4 a0 = *(const float4*)ap;
        float4 a1 = *(const float4*)(ap + 4);
        union { __hip_bfloat162 h2[4]; bf16x8 v; } ua;
        ua.h2[0] = __float22bfloat162_rn(make_float2(a0.x, a0.y));
        ua.h2[1] = __float22bfloat162_rn(make_float2(a0.z, a0.w));
        ua.h2[2] = __float22bfloat162_rn(make_float2(a1.x, a1.y));
        ua.h2[3] = __float22bfloat162_rn(make_float2(a1.z, a1.w));
        *(bf16x8*)(&As[0][ar * KP2 + ak]) = ua.v;
    }
    __syncthreads();

#pragma unroll
    for (int it = 0; it < 4; ++it) {
        const int buf = it & 1;
        float4 na0, na1;
        if (it < 3) {
            const float* ap = A + (size_t)(m0 + ar) * 256 + (it + 1) * 64 + ak;
            na0 = *(const float4*)ap;
            na1 = *(const float4*)(ap + 4);
        }
#pragma unroll
        for (int ks = 0; ks < 4; ++ks) {
            const int g = it * 4 + ks;
            bf16x8 af = *(const bf16x8*)(&As[buf][lm * KP2 + ks * 16 + lk]);
            bf16x8 b0 = *(const bf16x8*)(wf0 + (size_t)g * 4096);
            bf16x8 b1 = *(const bf16x8*)(wf0 + (size_t)g * 4096 + 256);
            // swapped operands -> C^T
            acc[0] = __builtin_amdgcn_mfma_f32_32x32x16_bf16(b0, af, acc[0], 0, 0, 0);
            acc[1] = __builtin_amdgcn_mfma_f32_32x32x16_bf16(b1, af, acc[1], 0, 0, 0);
        }
        if (it < 3) {
            union { __hip_bfloat162 h2[4]; bf16x8 v; } ua;
            ua.h2[0] = __float22bfloat162_rn(make_float2(na0.x, na0.y));
            ua.h2[1] = __float22bfloat162_rn(make_float2(na0.z, na0.w));
            ua.h2[2] = __float22bfloat162_rn(make_float2(na1.x, na1.y));
            ua.h2[3] = __float22bfloat162_rn(make_float2(na1.z, na1.w));
            *(bf16x8*)(&As[buf ^ 1][ar * KP2 + ak]) = ua.v;
            __syncthreads();
        }
    }

    // ---- epilogue: lane owns row m = m0+lm; n = wave*64 + j*32 + 8g+4kh + i ----
    const int m   = m0 + lm;
    const int b   = m / NT;
    const int pos = m - b * NT;
#pragma unroll
    for (int j = 0; j < 2; j++) {
        const int h = wave * 2 + j;
        __hip_bfloat16* vrow = V + ((size_t)(b * NH + h) * NT + pos) * HD;
#pragma unroll
        for (int g = 0; g < 4; g++) {
            const int d0 = g * 8 + kh * 4;
            const int n0 = wave * 64 + j * 32 + d0;
            float4 b4 = *(const float4*)(bias + n0);
            union { __hip_bfloat162 h2[2]; bf16x4 v; } u;
            u.h2[0] = __float22bfloat162_rn(
                make_float2(acc[j][g * 4 + 0] + b4.x, acc[j][g * 4 + 1] + b4.y));
            u.h2[1] = __float22bfloat162_rn(
                make_float2(acc[j][g * 4 + 2] + b4.z, acc[j][g * 4 + 3] + b4.w));
            *(bf16x4*)(vrow + d0) = u.v;
        }
    }
}

// ---------------------------------------------------------------------------
// Kernel 2 (MFMA): [off_raw | attn_raw] = query @ [W_off | W_attn] + bias.
// Swapped operands -> per-lane row m, float4 stores.
// ---------------------------------------------------------------------------
__global__ __launch_bounds__(192) void k_offattn(
    const float* __restrict__ Q,             // (4800, 256)
    const __hip_bfloat16* __restrict__ Wt2,  // tiled bf16 [W_off|W_attn]^T
    const float* __restrict__ boff,          // (192,)
    const float* __restrict__ battn,         // (96,)
    float* __restrict__ off_out,             // (4800, 192)
    float* __restrict__ attn_out)            // (4800, 96)
{
    __shared__ __hip_bfloat16 As[32 * KP];
    __shared__ __hip_bfloat16 Ws[288 * KP];

    const int t    = threadIdx.x;
    const int m0   = blockIdx.x * 32;
    const int wave = t >> 6;       // 0..2
    const int lane = t & 63;
    const int lm   = lane & 31;
    const int kh   = lane >> 5;
    const int lk   = kh * 8;

    f32x16 acc[3];
#pragma unroll
    for (int j = 0; j < 3; j++)
#pragma unroll
        for (int e = 0; e < 16; e++) acc[j][e] = 0.f;

    for (int kt = 0; kt < 256; kt += 32) {
        if (t < 128) {
            const int ar = t >> 2;
            const int ak = (t & 3) * 8;
            const float* ap = Q + (size_t)(m0 + ar) * 256 + kt + ak;
            float4 a0 = *(const float4*)ap;
            float4 a1 = *(const float4*)(ap + 4);
            union { __hip_bfloat162 h2[4]; bf16x8 v; } ua;
            ua.h2[0] = __float22bfloat162_rn(make_float2(a0.x, a0.y));
            ua.h2[1] = __float22bfloat162_rn(make_float2(a0.z, a0.w));
            ua.h2[2] = __float22bfloat162_rn(make_float2(a1.x, a1.y));
            ua.h2[3] = __float22bfloat162_rn(make_float2(a1.z, a1.w));
            *(bf16x8*)(As + ar * KP + ak) = ua.v;
        }
        {
            const __hip_bfloat16* wp = Wt2 + (size_t)(kt >> 5) * 9216 + t * 32;
            __hip_bfloat16* wd = Ws + t * KP;
            *(bf16x8*)(wd + 0)  = *(const bf16x8*)(wp + 0);
            *(bf16x8*)(wd + 8)  = *(const bf16x8*)(wp + 8);
            *(bf16x8*)(wd + 16) = *(const bf16x8*)(wp + 16);
            *(bf16x8*)(wd + 24) = *(const bf16x8*)(wp + 24);
            if (t < 96) {
                const __hip_bfloat16* wp2 = Wt2 + (size_t)(kt >> 5) * 9216 + (t + 192) * 32;
                __hip_bfloat16* wd2 = Ws + (t + 192) * KP;
                *(bf16x8*)(wd2 + 0)  = *(const bf16x8*)(wp2 + 0);
                *(bf16x8*)(wd2 + 8)  = *(const bf16x8*)(wp2 + 8);
                *(bf16x8*)(wd2 + 16) = *(const bf16x8*)(wp2 + 16);
                *(bf16x8*)(wd2 + 24) = *(const bf16x8*)(wp2 + 24);
            }
        }
        __syncthreads();

#pragma unroll
        for (int kk = 0; kk < 32; kk += 16) {
            bf16x8 af = *(const bf16x8*)(As + lm * KP + kk + lk);
#pragma unroll
            for (int j = 0; j < 3; j++) {
                bf16x8 bf = *(const bf16x8*)(Ws + (wave * 96 + j * 32 + lm) * KP + kk + lk);
                acc[j] = __builtin_amdgcn_mfma_f32_32x32x16_bf16(bf, af, acc[j], 0, 0, 0);
            }
        }
        __syncthreads();
    }

    const int m = m0 + lm;
#pragma unroll
    for (int j = 0; j < 3; j++) {
        const int nt_ = wave * 96 + j * 32;
#pragma unroll
        for (int g = 0; g < 4; g++) {
            const int n0 = nt_ + g * 8 + kh * 4;
            float4 o;
            if (nt_ < 192) {
                float4 b4 = *(const float4*)(boff + n0);
                o.x = acc[j][g * 4 + 0] + b4.x;
                o.y = acc[j][g * 4 + 1] + b4.y;
                o.z = acc[j][g * 4 + 2] + b4.z;
                o.w = acc[j][g * 4 + 3] + b4.w;
                *(float4*)(off_out + (size_t)m * 192 + n0) = o;
            } else {
                float4 b4 = *(const float4*)(battn + n0 - 192);
                o.x = acc[j][g * 4 + 0] + b4.x;
                o.y = acc[j][g * 4 + 1] + b4.y;
                o.z = acc[j][g * 4 + 2] + b4.z;
                o.w = acc[j][g * 4 + 3] + b4.w;
                *(float4*)(attn_out + (size_t)m * 96 + n0 - 192) = o;
            }
        }
    }
}

// ---------------------------------------------------------------------------
// Kernel 3: softmax + sampling.  4 queries per block (256 thr = 4 x 64).
// Thread = (query, head, 4-channel group); bf16x4 gathers (64-B segments
// per 8-lane head group); bf16x4 store.
// ---------------------------------------------------------------------------
__global__ __launch_bounds__(256) void k_sample(
    const float* __restrict__ off_raw,   // (4800, 192)  (h,l,p,2)
    const float* __restrict__ attn_raw,  // (4800, 96)   (h, l*4+p)
    const float* __restrict__ refp,      // (16, 300, 3, 2)
    const __hip_bfloat16* __restrict__ V,// (16, 8, 8400, 32)
    __hip_bfloat16* __restrict__ sampled)// (4800, 256) bf16
{
    const int t  = threadIdx.x;
    const int q4 = t >> 6;          // 0..3
    const int tq = t & 63;
    const int bq = blockIdx.x * 4 + q4;
    const int b  = bq / LQ;

    __shared__ float aw[4][96];
    __shared__ float wc[4][96][4];
    __shared__ int   ic[4][96][4];

    if (tq < 8) {
        float v[12];
        float mx = -1e30f;
#pragma unroll
        for (int i = 0; i < 12; i++) {
            v[i] = attn_raw[(size_t)bq * 96 + tq * 12 + i];
            mx = fmaxf(mx, v[i]);
        }
        float s = 0.f;
#pragma unroll
        for (int i = 0; i < 12; i++) { v[i] = expf(v[i] - mx); s += v[i]; }
        float inv = 1.f / s;
#pragma unroll
        for (int i = 0; i < 12; i++) aw[q4][tq * 12 + i] = v[i] * inv;
    }
    __syncthreads();

#pragma unroll
    for (int pp = tq; pp < 96; pp += 64) {
        const float dims[3]  = {80.f, 40.f, 20.f};
        const int startsl[3] = {0, 6400, 8000};
        const int idiml[3]   = {80, 40, 20};
        int h = pp / 12, lp = pp - h * 12, l = lp >> 2, p = lp & 3;
        float ox = off_raw[(size_t)bq * 192 + ((h * 3 + l) * 4 + p) * 2 + 0];
        float oy = off_raw[(size_t)bq * 192 + ((h * 3 + l) * 4 + p) * 2 + 1];
        float rx = refp[(size_t)bq * 6 + l * 2 + 0];
        float ry = refp[(size_t)bq * 6 + l * 2 + 1];
        float D  = dims[l];
        float lx = rx + ox / D;
        float ly = ry + oy / D;
        float ix = lx * D - 0.5f;
        float iy = ly * D - 0.5f;
        const int Dl = idiml[l];
        const int st = startsl[l];

        float fix = floorf(ix), fiy = floorf(iy);
        int ix0 = (int)fix, iy0 = (int)fiy;
        int ix1 = ix0 + 1, iy1 = iy0 + 1;
        float fx = ix - fix, fy = iy - fiy;

        float mx0 = (ix0 >= 0 && ix0 < Dl) ? 1.f : 0.f;
        float mx1 = (ix1 >= 0 && ix1 < Dl) ? 1.f : 0.f;
        float my0 = (iy0 >= 0 && iy0 < Dl) ? 1.f : 0.f;
        float my1 = (iy1 >= 0 && iy1 < Dl) ? 1.f : 0.f;

        int cx0 = min(max(ix0, 0), Dl - 1);
        int cx1 = min(max(ix1, 0), Dl - 1);
        int cy0 = min(max(iy0, 0), Dl - 1);
        int cy1 = min(max(iy1, 0), Dl - 1);

        float a = aw[q4][pp];
        wc[q4][pp][0] = (1.f - fx) * (1.f - fy) * mx0 * my0 * a;
        wc[q4][pp][1] = fx * (1.f - fy) * mx1 * my0 * a;
        wc[q4][pp][2] = (1.f - fx) * fy * mx0 * my1 * a;
        wc[q4][pp][3] = fx * fy * mx1 * my1 * a;
        ic[q4][pp][0] = (st + cy0 * Dl + cx0) * HD;
        ic[q4][pp][1] = (st + cy0 * Dl + cx1) * HD;
        ic[q4][pp][2] = (st + cy1 * Dl + cx0) * HD;
        ic[q4][pp][3] = (st + cy1 * Dl + cx1) * HD;
    }
    __syncthreads();

    const int h  = tq >> 3;          // 0..7
    const int dq = (tq & 7) * 4;     // 0..28
    const __hip_bfloat16* vb = V + (size_t)(b * NH + h) * NT * HD + dq;

    float a0 = 0.f, a1 = 0.f, a2 = 0.f, a3 = 0.f;
#pragma unroll
    for (int lp = 0; lp < 12; lp++) {
        const int s = h * 12 + lp;
        float4 w4 = *(const float4*)(&wc[q4][s][0]);
        int4   i4 = *(const int4*)(&ic[q4][s][0]);
        union { bf16x4 v; __hip_bfloat162 h2[2]; } c00, c01, c10, c11;
        c00.v = *(const bf16x4*)(vb + i4.x);
        c01.v = *(const bf16x4*)(vb + i4.y);
        c10.v = *(const bf16x4*)(vb + i4.z);
        c11.v = *(const bf16x4*)(vb + i4.w);
        float2 f00a = __bfloat1622float2(c00.h2[0]), f00b = __bfloat1622float2(c00.h2[1]);
        float2 f01a = __bfloat1622float2(c01.h2[0]), f01b = __bfloat1622float2(c01.h2[1]);
        float2 f10a = __bfloat1622float2(c10.h2[0]), f10b = __bfloat1622float2(c10.h2[1]);
        float2 f11a = __bfloat1622float2(c11.h2[0]), f11b = __bfloat1622float2(c11.h2[1]);
        a0 = fmaf(w4.x, f00a.x, fmaf(w4.y, f01a.x, fmaf(w4.z, f10a.x, fmaf(w4.w, f11a.x, a0))));
        a1 = fmaf(w4.x, f00a.y, fmaf(w4.y, f01a.y, fmaf(w4.z, f10a.y, fmaf(w4.w, f11a.y, a1))));
        a2 = fmaf(w4.x, f00b.x, fmaf(w4.y, f01b.x, fmaf(w4.z, f10b.x, fmaf(w4.w, f11b.x, a2))));
        a3 = fmaf(w4.x, f00b.y, fmaf(w4.y, f01b.y, fmaf(w4.z, f10b.y, fmaf(w4.w, f11b.y, a3))));
    }
    union { bf16x4 v; __hip_bfloat162 h2[2]; } uo;
    uo.h2[0] = __float22bfloat162_rn(make_float2(a0, a1));
    uo.h2[1] = __float22bfloat162_rn(make_float2(a2, a3));
    *(bf16x4*)(sampled + (size_t)bq * 256 + h * 32 + dq) = uo.v;
}

// ---------------------------------------------------------------------------
// Kernel 4 (MFMA): out = sampled(bf16) @ W_out + b_out.
// Swapped operands -> per-lane row m, float4 stores.
// ---------------------------------------------------------------------------
__global__ __launch_bounds__(256) void k_outproj(
    const __hip_bfloat16* __restrict__ A,    // (4800, 256) bf16
    const __hip_bfloat16* __restrict__ Wt3,  // tiled bf16 W_out^T
    const float* __restrict__ bias,          // (256,)
    float* __restrict__ out)                 // (4800, 256)
{
    __shared__ __hip_bfloat16 As[32 * KP];
    __shared__ __hip_bfloat16 Ws[256 * KP];

    const int t    = threadIdx.x;
    const int m0   = blockIdx.x * 32;
    const int wave = t >> 6;       // 0..3
    const int lane = t & 63;
    const int lm   = lane & 31;
    const int kh   = lane >> 5;
    const int lk   = kh * 8;

    f32x16 acc[2];
#pragma unroll
    for (int j = 0; j < 2; j++)
#pragma unroll
        for (int e = 0; e < 16; e++) acc[j][e] = 0.f;

    const int ar = t >> 3;         // 0..31
    const int ak = (t & 7) * 4;    // 0..28

    for (int kt = 0; kt < 256; kt += 32) {
        *(bf16x4*)(As + ar * KP + ak) =
            *(const bf16x4*)(A + (size_t)(m0 + ar) * 256 + kt + ak);
        {
            const __hip_bfloat16* wp = Wt3 + (size_t)(kt >> 5) * 8192 + t * 32;
            __hip_bfloat16* wd = Ws + t * KP;
            *(bf16x8*)(wd + 0)  = *(const bf16x8*)(wp + 0);
            *(bf16x8*)(wd + 8)  = *(const bf16x8*)(wp + 8);
            *(bf16x8*)(wd + 16) = *(const bf16x8*)(wp + 16);
            *(bf16x8*)(wd + 24) = *(const bf16x8*)(wp + 24);
        }
        __syncthreads();

#pragma unroll
        for (int kk = 0; kk < 32; kk += 16) {
            bf16x8 af = *(const bf16x8*)(As + lm * KP + kk + lk);
            bf16x8 bf0 = *(const bf16x8*)(Ws + (wave * 64 + 0 * 32 + lm) * KP + kk + lk);
            bf16x8 bf1 = *(const bf16x8*)(Ws + (wave * 64 + 1 * 32 + lm) * KP + kk + lk);
            acc[0] = __builtin_amdgcn_mfma_f32_32x32x16_bf16(bf0, af, acc[0], 0, 0, 0);
            acc[1] = __builtin_amdgcn_mfma_f32_32x32x16_bf16(bf1, af, acc[1], 0, 0, 0);
        }
        __syncthreads();
    }

    const int m = m0 + lm;
    float* orow = out + (size_t)m * 256;
#pragma unroll
    for (int j = 0; j < 2; j++) {
#pragma unroll
        for (int g = 0; g < 4; g++) {
            const int n0 = wave * 64 + j * 32 + g * 8 + kh * 4;
            float4 b4 = *(const float4*)(bias + n0);
            float4 o;
            o.x = acc[j][g * 4 + 0] + b4.x;
            o.y = acc[j][g * 4 + 1] + b4.y;
            o.z = acc[j][g * 4 + 2] + b4.z;
            o.w = acc[j][g * 4 + 3] + b4.w;
            *(float4*)(orow + n0) = o;
        }
    }
}

// ---------------------------------------------------------------------------
extern "C" void kernel_launch(void* const* d_in, const int* in_sizes, int n_in,
                              void* d_out, int out_size, void* d_ws, size_t ws_size,
                              hipStream_t stream) {
    const float* query  = (const float*)d_in[0];
    const float* refp   = (const float*)d_in[1];
    const float* inputf = (const float*)d_in[2];
    const float* W_off  = (const float*)d_in[3];
    const float* b_off  = (const float*)d_in[4];
    const float* W_attn = (const float*)d_in[5];
    const float* b_attn = (const float*)d_in[6];
    const float* W_val  = (const float*)d_in[7];
    const float* b_val  = (const float*)d_in[8];
    const float* W_out  = (const float*)d_in[9];
    const float* b_out  = (const float*)d_in[10];
    float* out = (float*)d_out;

    char* ws = (char*)d_ws;
    __hip_bfloat16* value   = (__hip_bfloat16*)ws;                       // 68,812,800
    float* off_raw          = (float*)(ws + 68812800);                   //  3,686,400
    float* attn_raw         = (float*)(ws + 72499200);                   //  1,843,200
    __hip_bfloat16* sampled = (__hip_bfloat16*)(ws + 74342400);          //  2,457,600
    __hip_bfloat16* Wf      = (__hip_bfloat16*)(ws + 76800000);          //    131,072
    __hip_bfloat16* Wt2     = (__hip_bfloat16*)(ws + 76931072);          //    147,456
    __hip_bfloat16* Wt3     = (__hip_bfloat16*)(ws + 77078528);          //    131,072

    k_wt<<<800, 256, 0, stream>>>(W_val, W_off, W_attn, W_out, Wf, Wt2, Wt3);
    k_valproj<<<MROWS / 32, 256, 0, stream>>>(inputf, Wf, b_val, value);
    k_offattn<<<QROWS / 32, 192, 0, stream>>>(query, Wt2, b_off, b_attn,
                                              off_raw, attn_raw);
    k_sample<<<QROWS / 4, 256, 0, stream>>>(off_raw, attn_raw, refp, value, sampled);
    k_outproj<<<QROWS / 32, 256, 0, stream>>>(sampled, Wt3, b_out, out);
}